// Round 2
// baseline (615.581 us; speedup 1.0000x reference)
//
#include <hip/hip_runtime.h>
#include <hip/hip_bf16.h>

#define NB 2000   // graph nodes
#define FN 128    // node features
#define DD 512    // embedding dim (H*GD)
#define HH 8      // heads
#define GG 64     // head dim
#define BB 64     // batch
#define SS 512    // region seq
#define TT 512    // trip seq

// ---------------------------------------------------------------------------
// Dtype-robust load/store: the harness may present float tensors as fp32 or
// bf16. We detect at runtime (see detect_kernel) and template the bodies.
// ---------------------------------------------------------------------------
template<bool BF>
__device__ __forceinline__ float ld(const void* p, long i) {
    if constexpr (BF) return __bfloat162float(((const __hip_bfloat16*)p)[i]);
    else              return ((const float*)p)[i];
}
template<bool BF>
__device__ __forceinline__ void st(void* p, long i, float v) {
    if constexpr (BF) ((__hip_bfloat16*)p)[i] = __float2bfloat16(v);
    else              ((float*)p)[i] = v;
}

// ---------------------------------------------------------------------------
// Kernel 0: dtype detection via graph_mask bit patterns.
// fp32 encoding of {0,1} gives words in {0x00000000, 0x3F800000} ONLY.
// bf16 encoding gives pair-words 0x00003F80 / 0x3F803F80 for (1,0)/(1,1)
// pairs — impossible in fp32 mode. Scan 131072 words (512 KB): bf16 mode has
// ~2500 expected unique-pattern words (2% density + diagonal self loops).
// ---------------------------------------------------------------------------
__global__ void detect_kernel(const unsigned int* __restrict__ w, int* flag) {
    __shared__ int found;
    if (threadIdx.x == 0) found = 0;
    __syncthreads();
    for (int i = threadIdx.x; i < 131072; i += blockDim.x) {
        unsigned v = w[i];
        if (v == 0x00003F80u || v == 0x3F803F80u) { found = 1; break; }
    }
    __syncthreads();
    if (threadIdx.x == 0) *flag = found;
}

// ---------------------------------------------------------------------------
// Kernel 1: h[h,n,g] = sum_f x[n,f] * W_gat[h,f,g]; es/ed per-head dots with
// a_src/a_dst via wave butterfly reduction. One block per node, 512 thr=(h,g).
// ---------------------------------------------------------------------------
template<bool BF>
__device__ __forceinline__ void gat_h_body(
    const void* __restrict__ x, const void* __restrict__ Wg,
    const void* __restrict__ a_src, const void* __restrict__ a_dst,
    float* __restrict__ h_ws, float* __restrict__ es_ws, float* __restrict__ ed_ws)
{
    int n   = blockIdx.x;
    int tid = threadIdx.x;
    int hh  = tid >> 6, g = tid & 63;
    __shared__ float xs[FN];
    if (tid < FN) xs[tid] = ld<BF>(x, n * FN + tid);
    __syncthreads();
    long wbase = (long)hh * FN * GG + g;
    float v = 0.f;
#pragma unroll 8
    for (int f = 0; f < FN; ++f) v += xs[f] * ld<BF>(Wg, wbase + f * GG);
    h_ws[(hh * NB + n) * GG + g] = v;
    float s1 = v * ld<BF>(a_src, hh * GG + g);
    float s2 = v * ld<BF>(a_dst, hh * GG + g);
    for (int off = 32; off > 0; off >>= 1) {
        s1 += __shfl_xor(s1, off);
        s2 += __shfl_xor(s2, off);
    }
    if (g == 0) { es_ws[hh * NB + n] = s1; ed_ws[hh * NB + n] = s2; }
}

__global__ __launch_bounds__(512) void gat_h_kernel(
    const void* x, const void* Wg, const void* a_src, const void* a_dst,
    float* h_ws, float* es_ws, float* ed_ws, const int* flag)
{
    if (*flag) gat_h_body<true >(x, Wg, a_src, a_dst, h_ws, es_ws, ed_ws);
    else       gat_h_body<false>(x, Wg, a_src, a_dst, h_ws, es_ws, ed_ws);
}

// ---------------------------------------------------------------------------
// Kernel 2: per-node GAT attention, online softmax over adjacency row in 4
// chunks of 512 columns. One block per node; wave hh owns head hh.
// ---------------------------------------------------------------------------
template<bool BF>
__device__ __forceinline__ void gat_attn_body(
    const void* __restrict__ adj,
    const float* __restrict__ h_ws, const float* __restrict__ es_ws,
    const float* __restrict__ ed_ws, float* __restrict__ ge_ws)
{
    int i   = blockIdx.x;
    int tid = threadIdx.x;
    int hh  = tid >> 6, g = tid & 63;
    __shared__ int   jl[512];
    __shared__ float eL[HH][512];
    __shared__ float es_i[HH];
    __shared__ int   cnt;
    if (tid < HH) es_i[tid] = es_ws[tid * NB + i];

    float m = -INFINITY, l = 0.f, acc = 0.f;
    const float* hp = h_ws + (long)hh * NB * GG + g;

    for (int c = 0; c < 4; ++c) {
        if (tid == 0) cnt = 0;
        __syncthreads();
        int  j     = c * 512 + tid;
        bool valid = (j < NB) && (ld<BF>(adj, (long)i * NB + j) > 0.f);
        if (valid) { int k = atomicAdd(&cnt, 1); jl[k] = j; }
        __syncthreads();
        int cn = cnt;
        if (tid < cn) {
            int j2 = jl[tid];
#pragma unroll
            for (int h = 0; h < HH; ++h) {
                float ev = es_i[h] + ed_ws[h * NB + j2];
                eL[h][tid] = ev > 0.f ? ev : 0.2f * ev;   // leaky_relu(0.2)
            }
        }
        __syncthreads();
        float cmax = -INFINITY;
        for (int k = g; k < cn; k += 64) cmax = fmaxf(cmax, eL[hh][k]);
        for (int off = 32; off > 0; off >>= 1) cmax = fmaxf(cmax, __shfl_xor(cmax, off));
        float m_new = fmaxf(m, cmax);
        float alpha;
        if (m_new == -INFINITY)      alpha = 1.f;   // nothing seen yet
        else if (m == -INFINITY)     alpha = 0.f;   // first valid chunk
        else                         alpha = __expf(m - m_new);
        float p = 0.f;
        for (int k = g; k < cn; k += 64) {
            float w = __expf(eL[hh][k] - m_new);
            eL[hh][k] = w;
            p += w;
        }
        for (int off = 32; off > 0; off >>= 1) p += __shfl_xor(p, off);
        l = l * alpha + p;
        m = m_new;
        __syncthreads();   // eL rows now hold unnormalized weights
        acc *= alpha;
        for (int k = 0; k < cn; ++k)
            acc += eL[hh][k] * hp[jl[k] * GG];
        __syncthreads();   // finish reads before next chunk rewrites jl/eL
    }
    float o = (l > 0.f) ? acc / l : 0.f;
    ge_ws[(long)i * DD + tid] = fmaxf(o, 0.f);   // relu
}

__global__ __launch_bounds__(512) void gat_attn_kernel(
    const void* adj, const float* h_ws, const float* es_ws,
    const float* ed_ws, float* ge_ws, const int* flag)
{
    if (*flag) gat_attn_body<true >(adj, h_ws, es_ws, ed_ws, ge_ws);
    else       gat_attn_body<false>(adj, h_ws, es_ws, ed_ws, ge_ws);
}

// ---------------------------------------------------------------------------
// Kernel 3: region output. Gather graph_emb by 1-based index (0 = pad -> 0),
// add cyclical time features @ W_time + b_time. One block per (b,s) row.
// ---------------------------------------------------------------------------
template<bool BF>
__device__ __forceinline__ void region_out_body(
    const int* __restrict__ index_array, const void* __restrict__ arrive,
    const void* __restrict__ region_mask,
    const void* __restrict__ W_time, const void* __restrict__ b_time,
    const float* __restrict__ ge_ws, void* __restrict__ out)
{
    int row = blockIdx.x;
    int d   = threadIdx.x;
    int idx = index_array[row];
    float mask = ld<BF>(region_mask, row);
    float t    = ld<BF>(arrive, row);
    float ang  = 6.28318530717958647692f * t / 86400.f;
    float sa = sinf(ang) * mask, ca = cosf(ang) * mask;
    float gv = (idx > 0) ? ge_ws[(long)(idx - 1) * DD + d] : 0.f;
    float o  = gv + sa * ld<BF>(W_time, d) + ca * ld<BF>(W_time, DD + d)
                  + ld<BF>(b_time, d);
    st<BF>(out, (long)row * DD + d, o);
}

__global__ __launch_bounds__(512) void region_out_kernel(
    const int* index_array, const void* arrive, const void* region_mask,
    const void* W_time, const void* b_time, const float* ge_ws, void* out,
    const int* flag)
{
    if (*flag) region_out_body<true >(index_array, arrive, region_mask, W_time, b_time, ge_ws, out);
    else       region_out_body<false>(index_array, arrive, region_mask, W_time, b_time, ge_ws, out);
}

// ---------------------------------------------------------------------------
// Kernel 4: trip output. relu(x_row @ W_trip) + time features. One block per
// (b,t) row; 256 threads, 2 output dims each; x row staged in LDS.
// ---------------------------------------------------------------------------
template<bool BF>
__device__ __forceinline__ void trip_out_body(
    const void* __restrict__ trip_batch, const void* __restrict__ W_trip,
    const void* __restrict__ depart, const void* __restrict__ trip_mask,
    const void* __restrict__ W_time, const void* __restrict__ b_time,
    void* __restrict__ out)
{
    int row = blockIdx.x;
    int tid = threadIdx.x;
    __shared__ float xs[FN];
    if (tid < FN) xs[tid] = ld<BF>(trip_batch, (long)row * FN + tid);
    __syncthreads();
    float a0 = 0.f, a1 = 0.f;
#pragma unroll 8
    for (int f = 0; f < FN; ++f) {
        float xf = xs[f];
        a0 += xf * ld<BF>(W_trip, f * DD + tid);
        a1 += xf * ld<BF>(W_trip, f * DD + tid + 256);
    }
    a0 = fmaxf(a0, 0.f);
    a1 = fmaxf(a1, 0.f);
    float mask = ld<BF>(trip_mask, row);
    float t    = ld<BF>(depart, row);
    float ang  = 6.28318530717958647692f * t / 86400.f;
    float sa = sinf(ang) * mask, ca = cosf(ang) * mask;
    int d0 = tid, d1 = tid + 256;
    float o0 = a0 + sa * ld<BF>(W_time, d0) + ca * ld<BF>(W_time, DD + d0) + ld<BF>(b_time, d0);
    float o1 = a1 + sa * ld<BF>(W_time, d1) + ca * ld<BF>(W_time, DD + d1) + ld<BF>(b_time, d1);
    long base = (long)BB * SS * DD + (long)row * DD;
    st<BF>(out, base + d0, o0);
    st<BF>(out, base + d1, o1);
}

__global__ __launch_bounds__(256) void trip_out_kernel(
    const void* trip_batch, const void* W_trip, const void* depart,
    const void* trip_mask, const void* W_time, const void* b_time, void* out,
    const int* flag)
{
    if (*flag) trip_out_body<true >(trip_batch, W_trip, depart, trip_mask, W_time, b_time, out);
    else       trip_out_body<false>(trip_batch, W_trip, depart, trip_mask, W_time, b_time, out);
}

extern "C" void kernel_launch(void* const* d_in, const int* in_sizes, int n_in,
                              void* d_out, int out_size, void* d_ws, size_t ws_size,
                              hipStream_t stream) {
    const void* region_batch = d_in[0];   // [2000,128]
    const void* trip_batch   = d_in[1];   // [64,512,128]
    const void* trip_mask    = d_in[2];   // [64,512]
    const void* region_mask  = d_in[3];   // [64,512]
    const void* graph_mask   = d_in[4];   // [2000,2000]
    const void* arrive       = d_in[5];   // [64,512]
    const void* depart       = d_in[6];   // [64,512]
    const int*  index_array  = (const int*)d_in[7];   // [64,512] int32
    const void* W_trip       = d_in[8];   // [128,512]
    const void* W_gat        = d_in[9];   // [8,128,64]
    const void* a_src        = d_in[10];  // [8,64]
    const void* a_dst        = d_in[11];  // [8,64]
    const void* W_time       = d_in[12];  // [2,512]
    const void* b_time       = d_in[13];  // [512]

    // fp32 workspace layout (~8.33 MB)
    float* h_ws  = (float*)d_ws;            // [8,2000,64]
    float* es_ws = h_ws  + HH * NB * GG;    // [8,2000]
    float* ed_ws = es_ws + HH * NB;         // [8,2000]
    float* ge_ws = ed_ws + HH * NB;         // [2000,512]
    int*   flag  = (int*)(ge_ws + (long)NB * DD);

    detect_kernel<<<1, 1024, 0, stream>>>((const unsigned int*)graph_mask, flag);
    gat_h_kernel<<<NB, 512, 0, stream>>>(region_batch, W_gat, a_src, a_dst,
                                         h_ws, es_ws, ed_ws, flag);
    gat_attn_kernel<<<NB, 512, 0, stream>>>(graph_mask, h_ws, es_ws, ed_ws, ge_ws, flag);
    region_out_kernel<<<BB * SS, 512, 0, stream>>>(index_array, arrive, region_mask,
                                                   W_time, b_time, ge_ws, d_out, flag);
    trip_out_kernel<<<BB * TT, 256, 0, stream>>>(trip_batch, W_trip, depart, trip_mask,
                                                 W_time, b_time, d_out, flag);
}